// Round 1
// baseline (638.001 us; speedup 1.0000x reference)
//
#include <hip/hip_runtime.h>

#define BATCH 8
#define SEQ   4096
#define CH    64

typedef __attribute__((ext_vector_type(8))) short bf16x8;   // 8 bf16 in 4 VGPRs
typedef __attribute__((ext_vector_type(4))) float f32x4;

__device__ __forceinline__ unsigned short f2bf(float f) {
    union { float f; unsigned int u; } v; v.f = f;
    unsigned int r = v.u + 0x7fffu + ((v.u >> 16) & 1u);   // RNE
    return (unsigned short)(r >> 16);
}
__device__ __forceinline__ float bf2f(unsigned short h) {
    union { float f; unsigned int u; } v; v.u = ((unsigned int)h) << 16;
    return v.f;
}

// ---------------------------------------------------------------------------
// K0: fold 1x1 convs into the shared 3-tap conv.
// Wc[T][t][i][c] = sum_m w1_T[0,i,m] * wd[t,m,c]
// bb[T][t][c]    = sum_m b1_T[m]     * wd[t,m,c]
// grid: 9 blocks (T*3+t), 256 threads
// ---------------------------------------------------------------------------
__global__ void combine_w_kernel(const float* __restrict__ wq, const float* __restrict__ bq,
                                 const float* __restrict__ wk, const float* __restrict__ bk,
                                 const float* __restrict__ wv, const float* __restrict__ bv,
                                 const float* __restrict__ wd,
                                 float* __restrict__ Wc, float* __restrict__ bb) {
    int T = blockIdx.x / 3, t = blockIdx.x % 3;
    const float* w1 = (T == 0) ? wq : (T == 1) ? wk : wv;
    const float* b1 = (T == 0) ? bq : (T == 1) ? bk : bv;
    const float* wdt = wd + t * CH * CH;
    float* out = Wc + (T * 3 + t) * CH * CH;
    for (int idx = threadIdx.x; idx < CH * CH; idx += blockDim.x) {
        int i = idx >> 6, c = idx & 63;
        float acc = 0.f;
        for (int m = 0; m < CH; ++m) acc = fmaf(w1[i * CH + m], wdt[m * CH + c], acc);
        out[idx] = acc;
    }
    if (threadIdx.x < CH) {
        int c = threadIdx.x;
        float acc = 0.f;
        for (int m = 0; m < CH; ++m) acc = fmaf(b1[m], wdt[m * CH + c], acc);
        bb[(T * 3 + t) * CH + c] = acc;
    }
}

// ---------------------------------------------------------------------------
// K1: fused conv (1x1 + 3-tap) for Q,K,V.
//   Y[b,l,c] = sum_t sum_i X[b,l+t-1,i] * Wc[T][t][i][c] + bias(l,c)
// Outputs: Q -> Qh,Ql (bf16 split, row-major); K -> Kh,Kl; V -> Vt (bf16, transposed [b][d][l])
// grid: (B*SEQ/32, 3), 256 threads. Wave w handles 8 rows.
// ---------------------------------------------------------------------------
#define CROWS 32
__global__ __launch_bounds__(256) void qkv_conv_kernel(
        const float* __restrict__ Q, const float* __restrict__ K, const float* __restrict__ V,
        const float* __restrict__ Wc, const float* __restrict__ bb, const float* __restrict__ bd,
        unsigned short* __restrict__ Qh, unsigned short* __restrict__ Ql,
        unsigned short* __restrict__ Kh, unsigned short* __restrict__ Kl,
        unsigned short* __restrict__ Vt) {
    int T = blockIdx.y;
    const float* X = (T == 0) ? Q : (T == 1) ? K : V;
    int rowblk = blockIdx.x;
    int b  = rowblk / (SEQ / CROWS);
    int l0 = (rowblk % (SEQ / CROWS)) * CROWS;

    __shared__ float Ws[3][CH][65];        // [t][c][i], stride 65 -> conflict-free b32 reads
    __shared__ float xs[CROWS + 2][CH];    // halo rows
    __shared__ float biasS[CH];
    __shared__ float bbS[3][CH];
    __shared__ unsigned short ys[CH][40];  // V transpose staging (only T==2)

    int tid = threadIdx.x;
    for (int idx = tid; idx < 3 * CH * CH; idx += 256) {
        int t = idx >> 12, rem = idx & 4095;
        int i = rem >> 6, c = rem & 63;
        Ws[t][c][i] = Wc[(T * 3 + t) * CH * CH + rem];
    }
    if (tid < CH) biasS[tid] = bd[tid];
    for (int idx = tid; idx < 3 * CH; idx += 256)
        bbS[idx >> 6][idx & 63] = bb[T * 3 * CH + idx];
    for (int idx = tid; idx < (CROWS + 2) * CH; idx += 256) {
        int rr = idx >> 6, cc = idx & 63;
        int gl = l0 + rr - 1;
        xs[rr][cc] = (gl >= 0 && gl < SEQ) ? X[((size_t)b * SEQ + gl) * CH + cc] : 0.f;
    }
    __syncthreads();

    int wave = tid >> 6, lane = tid & 63;
    int lr0 = wave * 8;
    float acc[8];
#pragma unroll
    for (int r = 0; r < 8; ++r) {
        int gl = l0 + lr0 + r;
        float bias = biasS[lane] + bbS[1][lane];
        if (gl > 0)       bias += bbS[0][lane];
        if (gl < SEQ - 1) bias += bbS[2][lane];
        acc[r] = bias;
    }
    for (int t = 0; t < 3; ++t) {
#pragma unroll
        for (int i = 0; i < CH; i += 4) {
            float w0 = Ws[t][lane][i + 0], w1 = Ws[t][lane][i + 1];
            float w2 = Ws[t][lane][i + 2], w3 = Ws[t][lane][i + 3];
#pragma unroll
            for (int r = 0; r < 8; ++r) {
                const float* xr = &xs[lr0 + r + t][i];
                acc[r] = fmaf(xr[0], w0, acc[r]);
                acc[r] = fmaf(xr[1], w1, acc[r]);
                acc[r] = fmaf(xr[2], w2, acc[r]);
                acc[r] = fmaf(xr[3], w3, acc[r]);
            }
        }
    }

    size_t base = ((size_t)b * SEQ + l0 + lr0) * CH + lane;
    if (T == 0) {
#pragma unroll
        for (int r = 0; r < 8; ++r) {
            float x = acc[r];
            unsigned short h = f2bf(x);
            Qh[base + (size_t)r * CH] = h;
            Ql[base + (size_t)r * CH] = f2bf(x - bf2f(h));
        }
    } else if (T == 1) {
#pragma unroll
        for (int r = 0; r < 8; ++r) {
            float x = acc[r];
            unsigned short h = f2bf(x);
            Kh[base + (size_t)r * CH] = h;
            Kl[base + (size_t)r * CH] = f2bf(x - bf2f(h));
        }
    } else {
#pragma unroll
        for (int r = 0; r < 8; ++r) ys[lane][lr0 + r] = f2bf(acc[r]);
        __syncthreads();   // T uniform per block: safe
        int c = tid >> 2, seg = tid & 3;
        bf16x8 v = *(const bf16x8*)&ys[c][seg * 8];
        *(bf16x8*)(Vt + ((size_t)b * CH + c) * SEQ + l0 + seg * 8) = v;
    }
}

// ---------------------------------------------------------------------------
// K2: flash attention. grid: 512 blocks (b = bid&7 -> XCD-aligned batches),
// 256 threads = 4 waves, each wave owns 16 q-rows. KV tile = 32 keys.
// Scores: 3-product bf16-split MFMA (fp32-accurate). P->bf16 via wave-private
// LDS transpose. PV: A=P[16x32], B=Vt fragments (contiguous loads).
// ---------------------------------------------------------------------------
__global__ __launch_bounds__(256) void attn_kernel(
        const unsigned short* __restrict__ Qh, const unsigned short* __restrict__ Ql,
        const unsigned short* __restrict__ Kh, const unsigned short* __restrict__ Kl,
        const unsigned short* __restrict__ Vt, float* __restrict__ O) {
    int bid  = blockIdx.x;
    int b    = bid & 7;          // batch == XCD (round-robin dispatch)
    int qt   = bid >> 3;
    int wave = threadIdx.x >> 6;
    int lane = threadIdx.x & 63;
    int g = lane >> 4, c = lane & 15;
    int q0 = qt * 64 + wave * 16;

    __shared__ unsigned short pbuf[4][16][40];   // per-wave P transpose, pad 40 -> 2-way max
    unsigned short (*pb)[40] = pbuf[wave];

    const size_t qoff = ((size_t)b * SEQ + q0 + c) * CH + g * 8;   // A rows = lane&15
    bf16x8 qh0 = *(const bf16x8*)(Qh + qoff);
    bf16x8 qh1 = *(const bf16x8*)(Qh + qoff + 32);
    bf16x8 ql0 = *(const bf16x8*)(Ql + qoff);
    bf16x8 ql1 = *(const bf16x8*)(Ql + qoff + 32);

    f32x4 o0 = {0,0,0,0}, o1 = {0,0,0,0}, o2 = {0,0,0,0}, o3 = {0,0,0,0};
    float mreg[4] = {-1e30f, -1e30f, -1e30f, -1e30f};
    float lreg[4] = {0.f, 0.f, 0.f, 0.f};

    const unsigned short* Kbh = Kh + (size_t)b * SEQ * CH;
    const unsigned short* Kbl = Kl + (size_t)b * SEQ * CH;
    const unsigned short* Vb  = Vt + (size_t)b * CH * SEQ;

    for (int kb = 0; kb < SEQ; kb += 32) {
        size_t k0off = ((size_t)(kb + c)) * CH + g * 8;        // B cols = lane&15 (key)
        size_t k1off = ((size_t)(kb + 16 + c)) * CH + g * 8;
        bf16x8 kh00 = *(const bf16x8*)(Kbh + k0off);
        bf16x8 kh01 = *(const bf16x8*)(Kbh + k0off + 32);
        bf16x8 kl00 = *(const bf16x8*)(Kbl + k0off);
        bf16x8 kl01 = *(const bf16x8*)(Kbl + k0off + 32);
        bf16x8 kh10 = *(const bf16x8*)(Kbh + k1off);
        bf16x8 kh11 = *(const bf16x8*)(Kbh + k1off + 32);
        bf16x8 kl10 = *(const bf16x8*)(Kbl + k1off);
        bf16x8 kl11 = *(const bf16x8*)(Kbl + k1off + 32);

        f32x4 s0 = {0,0,0,0}, s1 = {0,0,0,0};
        // hi*hi + hi*lo + lo*hi: ~fp32-accurate scores
        s0 = __builtin_amdgcn_mfma_f32_16x16x32_bf16(qh0, kh00, s0, 0, 0, 0);
        s0 = __builtin_amdgcn_mfma_f32_16x16x32_bf16(qh1, kh01, s0, 0, 0, 0);
        s0 = __builtin_amdgcn_mfma_f32_16x16x32_bf16(qh0, kl00, s0, 0, 0, 0);
        s0 = __builtin_amdgcn_mfma_f32_16x16x32_bf16(qh1, kl01, s0, 0, 0, 0);
        s0 = __builtin_amdgcn_mfma_f32_16x16x32_bf16(ql0, kh00, s0, 0, 0, 0);
        s0 = __builtin_amdgcn_mfma_f32_16x16x32_bf16(ql1, kh01, s0, 0, 0, 0);
        s1 = __builtin_amdgcn_mfma_f32_16x16x32_bf16(qh0, kh10, s1, 0, 0, 0);
        s1 = __builtin_amdgcn_mfma_f32_16x16x32_bf16(qh1, kh11, s1, 0, 0, 0);
        s1 = __builtin_amdgcn_mfma_f32_16x16x32_bf16(qh0, kl10, s1, 0, 0, 0);
        s1 = __builtin_amdgcn_mfma_f32_16x16x32_bf16(qh1, kl11, s1, 0, 0, 0);
        s1 = __builtin_amdgcn_mfma_f32_16x16x32_bf16(ql0, kh10, s1, 0, 0, 0);
        s1 = __builtin_amdgcn_mfma_f32_16x16x32_bf16(ql1, kh11, s1, 0, 0, 0);

        // online softmax; C/D rows = (lane>>4)*4 + r, cols = lane&15
        float scale[4], p0v[4], p1v[4];
#pragma unroll
        for (int r = 0; r < 4; ++r) {
            float mx = fmaxf(s0[r], s1[r]);
            mx = fmaxf(mx, __shfl_xor(mx, 1));
            mx = fmaxf(mx, __shfl_xor(mx, 2));
            mx = fmaxf(mx, __shfl_xor(mx, 4));
            mx = fmaxf(mx, __shfl_xor(mx, 8));
            float mn = fmaxf(mreg[r], mx);
            float sc = __expf(mreg[r] - mn);
            mreg[r] = mn;
            float p0 = __expf(s0[r] - mn);
            float p1 = __expf(s1[r] - mn);
            float ts = p0 + p1;
            ts += __shfl_xor(ts, 1);
            ts += __shfl_xor(ts, 2);
            ts += __shfl_xor(ts, 4);
            ts += __shfl_xor(ts, 8);
            lreg[r] = lreg[r] * sc + ts;
            scale[r] = sc;
            p0v[r] = p0; p1v[r] = p1;
        }
#pragma unroll
        for (int r = 0; r < 4; ++r) {
            o0[r] *= scale[r]; o1[r] *= scale[r];
            o2[r] *= scale[r]; o3[r] *= scale[r];
        }
        // transpose P to A-fragment layout (wave-private LDS; HW keeps same-wave DS ordered)
#pragma unroll
        for (int r = 0; r < 4; ++r) {
            pb[g * 4 + r][c]      = f2bf(p0v[r]);
            pb[g * 4 + r][16 + c] = f2bf(p1v[r]);
        }
        bf16x8 pa = *(const bf16x8*)&pb[c][g * 8];   // A rows = lane&15, k = g*8..+7

        {
            bf16x8 vf0 = *(const bf16x8*)(Vb + ((size_t)(0 * 16 + c)) * SEQ + kb + g * 8);
            bf16x8 vf1 = *(const bf16x8*)(Vb + ((size_t)(1 * 16 + c)) * SEQ + kb + g * 8);
            bf16x8 vf2 = *(const bf16x8*)(Vb + ((size_t)(2 * 16 + c)) * SEQ + kb + g * 8);
            bf16x8 vf3 = *(const bf16x8*)(Vb + ((size_t)(3 * 16 + c)) * SEQ + kb + g * 8);
            o0 = __builtin_amdgcn_mfma_f32_16x16x32_bf16(pa, vf0, o0, 0, 0, 0);
            o1 = __builtin_amdgcn_mfma_f32_16x16x32_bf16(pa, vf1, o1, 0, 0, 0);
            o2 = __builtin_amdgcn_mfma_f32_16x16x32_bf16(pa, vf2, o2, 0, 0, 0);
            o3 = __builtin_amdgcn_mfma_f32_16x16x32_bf16(pa, vf3, o3, 0, 0, 0);
        }
    }

#pragma unroll
    for (int r = 0; r < 4; ++r) {
        float inv = 1.f / lreg[r];
        o0[r] *= inv; o1[r] *= inv; o2[r] *= inv; o3[r] *= inv;
    }
    float* Ob = O + ((size_t)b * SEQ + q0) * CH;
#pragma unroll
    for (int r = 0; r < 4; ++r) {
        Ob[(g * 4 + r) * CH +  0 + c] = o0[r];
        Ob[(g * 4 + r) * CH + 16 + c] = o1[r];
        Ob[(g * 4 + r) * CH + 32 + c] = o2[r];
        Ob[(g * 4 + r) * CH + 48 + c] = o3[r];
    }
}

// ---------------------------------------------------------------------------
// K3: final 1x1 conv: out[b,l,c] = sum_i O[b,l,i]*wo[0,i,c] + bo[c]  (fp32)
// grid: 512 blocks x 64 rows, 256 threads (wave = 16 rows)
// ---------------------------------------------------------------------------
__global__ __launch_bounds__(256) void out_conv_kernel(
        const float* __restrict__ O, const float* __restrict__ wo,
        const float* __restrict__ bo, float* __restrict__ out) {
    int rowblk = blockIdx.x;
    int b  = rowblk / (SEQ / 64);
    int l0 = (rowblk % (SEQ / 64)) * 64;
    __shared__ float Ws[CH][65];   // [c][i]
    __shared__ float xs[64][CH];
    int tid = threadIdx.x;
    for (int idx = tid; idx < CH * CH; idx += 256) {
        int i = idx >> 6, cc = idx & 63;
        Ws[cc][i] = wo[idx];
    }
    for (int idx = tid; idx < 64 * CH; idx += 256) {
        int rr = idx >> 6, cc = idx & 63;
        xs[rr][cc] = O[((size_t)b * SEQ + l0 + rr) * CH + cc];
    }
    __syncthreads();
    int wave = tid >> 6, lane = tid & 63;
    int lr0 = wave * 16;
    float acc[16];
    float bias = bo[lane];
#pragma unroll
    for (int r = 0; r < 16; ++r) acc[r] = bias;
    for (int i = 0; i < CH; i += 4) {
        float w0 = Ws[lane][i], w1 = Ws[lane][i + 1], w2 = Ws[lane][i + 2], w3 = Ws[lane][i + 3];
#pragma unroll
        for (int r = 0; r < 16; ++r) {
            const float* xr = &xs[lr0 + r][i];
            acc[r] = fmaf(xr[0], w0, acc[r]);
            acc[r] = fmaf(xr[1], w1, acc[r]);
            acc[r] = fmaf(xr[2], w2, acc[r]);
            acc[r] = fmaf(xr[3], w3, acc[r]);
        }
    }
    float* ob = out + ((size_t)b * SEQ + l0 + lr0) * CH + lane;
#pragma unroll
    for (int r = 0; r < 16; ++r) ob[(size_t)r * CH] = acc[r];
}

// ---------------------------------------------------------------------------
extern "C" void kernel_launch(void* const* d_in, const int* in_sizes, int n_in,
                              void* d_out, int out_size, void* d_ws, size_t ws_size,
                              hipStream_t stream) {
    (void)in_sizes; (void)n_in; (void)out_size; (void)ws_size;
    const float* Q  = (const float*)d_in[0];
    const float* K  = (const float*)d_in[1];
    const float* V  = (const float*)d_in[2];
    const float* wq = (const float*)d_in[3];
    const float* bq = (const float*)d_in[4];
    const float* wk = (const float*)d_in[5];
    const float* bk = (const float*)d_in[6];
    const float* wv = (const float*)d_in[7];
    const float* bv = (const float*)d_in[8];
    const float* wd = (const float*)d_in[9];
    const float* bd = (const float*)d_in[10];
    const float* wo = (const float*)d_in[11];
    const float* bo = (const float*)d_in[12];
    float* out = (float*)d_out;

    const size_t NEL = (size_t)BATCH * SEQ * CH;   // 2097152
    char* ws = (char*)d_ws;
    float* Wc = (float*)(ws);                       // 9*64*64*4   = 147456 B
    float* bb = (float*)(ws + 147456);              // 9*64*4      = 2304 B
    unsigned short* Qh = (unsigned short*)(ws + 262144);
    unsigned short* Ql = Qh + NEL;
    unsigned short* Kh = Ql + NEL;
    unsigned short* Kl = Kh + NEL;
    unsigned short* Vt = Kl + NEL;
    float* Obuf = (float*)(ws + 262144 + 5 * NEL * sizeof(unsigned short));
    // total ws use: 262144 + 5*4 MiB + 8 MiB = ~28.3 MiB

    combine_w_kernel<<<9, 256, 0, stream>>>(wq, bq, wk, bk, wv, bv, wd, Wc, bb);
    qkv_conv_kernel<<<dim3(BATCH * SEQ / CROWS, 3), 256, 0, stream>>>(
        Q, K, V, Wc, bb, bd, Qh, Ql, Kh, Kl, Vt);
    attn_kernel<<<dim3((SEQ / 64) * BATCH), 256, 0, stream>>>(Qh, Ql, Kh, Kl, Vt, Obuf);
    out_conv_kernel<<<BATCH * SEQ / 64, 256, 0, stream>>>(Obuf, wo, bo, out);
}

// Round 2
// 530.684 us; speedup vs baseline: 1.2022x; 1.2022x over previous
//
#include <hip/hip_runtime.h>

#define BATCH 8
#define SEQ   4096
#define CH    64
#define KDIM  192   // 3 taps x 64 channels

typedef __attribute__((ext_vector_type(8))) short bf16x8;   // 8 bf16 in 4 VGPRs
typedef __attribute__((ext_vector_type(4))) float f32x4;

__device__ __forceinline__ unsigned short f2bf(float f) {
    union { float f; unsigned int u; } v; v.f = f;
    unsigned int r = v.u + 0x7fffu + ((v.u >> 16) & 1u);   // RNE
    return (unsigned short)(r >> 16);
}
__device__ __forceinline__ float bf2f(unsigned short h) {
    union { float f; unsigned int u; } v; v.u = ((unsigned int)h) << 16;
    return v.f;
}

// ---------------------------------------------------------------------------
// K0: fold 1x1 convs into the shared 3-tap conv; emit TRANSPOSED hi/lo split
// weights for the MFMA conv:  Wt[T][c][t*64+i] = (w1_T @ wd[t])[i][c]
// bbp[T*3+t][c] = sum_m b1_T[m] * wd[t][m][c]
// grid: 9 blocks (T*3+t), 256 threads
// ---------------------------------------------------------------------------
__global__ void combine_w_kernel(const float* __restrict__ wq, const float* __restrict__ bq,
                                 const float* __restrict__ wk, const float* __restrict__ bk,
                                 const float* __restrict__ wv, const float* __restrict__ bv,
                                 const float* __restrict__ wd,
                                 unsigned short* __restrict__ Wth, unsigned short* __restrict__ Wtl,
                                 float* __restrict__ bbp) {
    int T = blockIdx.x / 3, t = blockIdx.x % 3;
    const float* w1 = (T == 0) ? wq : (T == 1) ? wk : wv;
    const float* b1 = (T == 0) ? bq : (T == 1) ? bk : bv;
    const float* wdt = wd + t * CH * CH;
    for (int idx = threadIdx.x; idx < CH * CH; idx += blockDim.x) {
        int i = idx >> 6, c = idx & 63;
        float acc = 0.f;
        for (int m = 0; m < CH; ++m) acc = fmaf(w1[i * CH + m], wdt[m * CH + c], acc);
        unsigned short h = f2bf(acc);
        size_t o = ((size_t)(T * CH + c)) * KDIM + t * CH + i;
        Wth[o] = h;
        Wtl[o] = f2bf(acc - bf2f(h));
    }
    if (threadIdx.x < CH) {
        int c = threadIdx.x;
        float acc = 0.f;
        for (int m = 0; m < CH; ++m) acc = fmaf(b1[m], wdt[m * CH + c], acc);
        bbp[(T * 3 + t) * CH + c] = acc;
    }
}

// ---------------------------------------------------------------------------
// K1: MFMA conv. Out[b,l,c] = sum_{k<192} A[l][k] * W[k][c] + bias,
//     A[l][k] = X[b, l + k/64 - 1, k%64].
// X staged in LDS as hi/lo bf16 with XOR swizzle (conflict-free b128 reads).
// 3-product split MFMA: Xh*Wh + Xl*Wh + Xh*Wl  (~fp32-accurate).
// grid: (512, 3) blocks of 256 threads; block = 64 rows; wave = 16 rows.
// ---------------------------------------------------------------------------
__global__ __launch_bounds__(256) void conv_mfma_kernel(
        const float* __restrict__ Q, const float* __restrict__ K, const float* __restrict__ V,
        const unsigned short* __restrict__ Wth, const unsigned short* __restrict__ Wtl,
        const float* __restrict__ bbp, const float* __restrict__ bd,
        unsigned short* __restrict__ Qh, unsigned short* __restrict__ Ql,
        unsigned short* __restrict__ Kh, unsigned short* __restrict__ Kl,
        unsigned short* __restrict__ Vt) {
    int T = blockIdx.y;
    const float* X = (T == 0) ? Q : (T == 1) ? K : V;
    int rowblk = blockIdx.x;          // 0..511
    int b  = rowblk >> 6;             // 64 blocks per batch
    int l0 = (rowblk & 63) << 6;

    __shared__ unsigned short xh[66][64];   // rows l0-1 .. l0+64, XOR-swizzled inner idx
    __shared__ unsigned short xl[66][64];

    int tid = threadIdx.x;
    for (int q4 = tid; q4 < 66 * 16; q4 += 256) {
        int row = q4 >> 4, i = (q4 & 15) << 2;
        int gl = l0 + row - 1;
        float4 v = make_float4(0.f, 0.f, 0.f, 0.f);
        if (gl >= 0 && gl < SEQ) v = *(const float4*)(X + ((size_t)b * SEQ + gl) * CH + i);
        unsigned short h0 = f2bf(v.x), h1 = f2bf(v.y), h2 = f2bf(v.z), h3 = f2bf(v.w);
        unsigned short e0 = f2bf(v.x - bf2f(h0)), e1 = f2bf(v.y - bf2f(h1));
        unsigned short e2 = f2bf(v.z - bf2f(h2)), e3 = f2bf(v.w - bf2f(h3));
        int sw = i ^ ((row & 7) << 3);
        uint2 hp = { (unsigned)h0 | ((unsigned)h1 << 16), (unsigned)h2 | ((unsigned)h3 << 16) };
        uint2 lp = { (unsigned)e0 | ((unsigned)e1 << 16), (unsigned)e2 | ((unsigned)e3 << 16) };
        *(uint2*)&xh[row][sw] = hp;
        *(uint2*)&xl[row][sw] = lp;
    }
    __syncthreads();

    int wave = tid >> 6, lane = tid & 63;
    int g = lane >> 4, cc = lane & 15;
    int wrow0 = wave << 4;

    // A fragments: rows = cc, k = kk*32 + g*8 .. +7 ;  t = kk>>1, i = (kk&1)*32 + g*8
    bf16x8 ah[6], al[6];
#pragma unroll
    for (int kk = 0; kk < 6; ++kk) {
        int t = kk >> 1;
        int u = wrow0 + cc + t;
        int blk = (((kk & 1) * 4 + g) ^ (u & 7));
        ah[kk] = *(const bf16x8*)&xh[u][blk << 3];
        al[kk] = *(const bf16x8*)&xl[u][blk << 3];
    }

    for (int nt = 0; nt < 4; ++nt) {
        int col = nt * 16 + cc;
        const unsigned short* wbh = Wth + ((size_t)(T * CH + col)) * KDIM;
        const unsigned short* wbl = Wtl + ((size_t)(T * CH + col)) * KDIM;
        f32x4 acc = {0.f, 0.f, 0.f, 0.f};
#pragma unroll
        for (int kk = 0; kk < 6; ++kk) {
            bf16x8 bh = *(const bf16x8*)(wbh + kk * 32 + g * 8);
            bf16x8 bl = *(const bf16x8*)(wbl + kk * 32 + g * 8);
            acc = __builtin_amdgcn_mfma_f32_16x16x32_bf16(ah[kk], bh, acc, 0, 0, 0);
            acc = __builtin_amdgcn_mfma_f32_16x16x32_bf16(al[kk], bh, acc, 0, 0, 0);
            acc = __builtin_amdgcn_mfma_f32_16x16x32_bf16(ah[kk], bl, acc, 0, 0, 0);
        }
        float bias = bd[col] + bbp[(T * 3 + 0) * CH + col] + bbp[(T * 3 + 1) * CH + col]
                   + bbp[(T * 3 + 2) * CH + col];
#pragma unroll
        for (int r = 0; r < 4; ++r) {
            int gl = l0 + wrow0 + g * 4 + r;
            float v = acc[r] + bias;
            if (gl == 0)       v -= bbp[(T * 3 + 0) * CH + col];
            if (gl == SEQ - 1) v -= bbp[(T * 3 + 2) * CH + col];
            if (T == 0) {
                unsigned short h = f2bf(v);
                Qh[((size_t)b * SEQ + gl) * CH + col] = h;
                Ql[((size_t)b * SEQ + gl) * CH + col] = f2bf(v - bf2f(h));
            } else if (T == 1) {
                unsigned short h = f2bf(v);
                Kh[((size_t)b * SEQ + gl) * CH + col] = h;
                Kl[((size_t)b * SEQ + gl) * CH + col] = f2bf(v - bf2f(h));
            } else {
                Vt[((size_t)b * CH + col) * SEQ + gl] = f2bf(v);
            }
        }
    }
}

// ---------------------------------------------------------------------------
// K2: split-K flash attention. grid: 512*NS blocks (b = bid&7 -> XCD-aligned),
// 256 threads = 4 waves, wave = 16 q-rows, KV tile = 32 keys, seg = SEQ/NS.
// Deferred l-sum: per-lane partials in the loop, one shfl tree at the end.
// ---------------------------------------------------------------------------
__global__ __launch_bounds__(256) void attn_kernel(
        const unsigned short* __restrict__ Qh, const unsigned short* __restrict__ Ql,
        const unsigned short* __restrict__ Kh, const unsigned short* __restrict__ Kl,
        const unsigned short* __restrict__ Vt,
        float* __restrict__ Opart, float* __restrict__ Mp, float* __restrict__ Lp,
        float* __restrict__ Obuf, int seg_len, int normalize) {
    int bid  = blockIdx.x;
    int s    = bid >> 9;
    int b    = bid & 7;
    int qt   = (bid >> 3) & 63;
    int wave = threadIdx.x >> 6;
    int lane = threadIdx.x & 63;
    int g = lane >> 4, c = lane & 15;
    int q0 = qt * 64 + wave * 16;

    __shared__ unsigned short pbuf[4][16][40];   // per-wave P transpose
    unsigned short (*pb)[40] = pbuf[wave];

    const size_t qoff = ((size_t)b * SEQ + q0 + c) * CH + g * 8;
    bf16x8 qh0 = *(const bf16x8*)(Qh + qoff);
    bf16x8 qh1 = *(const bf16x8*)(Qh + qoff + 32);
    bf16x8 ql0 = *(const bf16x8*)(Ql + qoff);
    bf16x8 ql1 = *(const bf16x8*)(Ql + qoff + 32);

    f32x4 o0 = {0,0,0,0}, o1 = {0,0,0,0}, o2 = {0,0,0,0}, o3 = {0,0,0,0};
    float mreg[4] = {-1e30f, -1e30f, -1e30f, -1e30f};
    float lreg[4] = {0.f, 0.f, 0.f, 0.f};

    const unsigned short* Kbh = Kh + (size_t)b * SEQ * CH;
    const unsigned short* Kbl = Kl + (size_t)b * SEQ * CH;
    const unsigned short* Vb  = Vt + (size_t)b * CH * SEQ;

    int kbeg = s * seg_len, kend = kbeg + seg_len;
    for (int kb = kbeg; kb < kend; kb += 32) {
        size_t k0off = ((size_t)(kb + c)) * CH + g * 8;
        size_t k1off = ((size_t)(kb + 16 + c)) * CH + g * 8;
        bf16x8 kh00 = *(const bf16x8*)(Kbh + k0off);
        bf16x8 kh01 = *(const bf16x8*)(Kbh + k0off + 32);
        bf16x8 kl00 = *(const bf16x8*)(Kbl + k0off);
        bf16x8 kl01 = *(const bf16x8*)(Kbl + k0off + 32);
        bf16x8 kh10 = *(const bf16x8*)(Kbh + k1off);
        bf16x8 kh11 = *(const bf16x8*)(Kbh + k1off + 32);
        bf16x8 kl10 = *(const bf16x8*)(Kbl + k1off);
        bf16x8 kl11 = *(const bf16x8*)(Kbl + k1off + 32);

        f32x4 s0 = {0,0,0,0}, s1 = {0,0,0,0};
        s0 = __builtin_amdgcn_mfma_f32_16x16x32_bf16(qh0, kh00, s0, 0, 0, 0);
        s0 = __builtin_amdgcn_mfma_f32_16x16x32_bf16(qh1, kh01, s0, 0, 0, 0);
        s0 = __builtin_amdgcn_mfma_f32_16x16x32_bf16(qh0, kl00, s0, 0, 0, 0);
        s0 = __builtin_amdgcn_mfma_f32_16x16x32_bf16(qh1, kl01, s0, 0, 0, 0);
        s0 = __builtin_amdgcn_mfma_f32_16x16x32_bf16(ql0, kh00, s0, 0, 0, 0);
        s0 = __builtin_amdgcn_mfma_f32_16x16x32_bf16(ql1, kh01, s0, 0, 0, 0);
        s1 = __builtin_amdgcn_mfma_f32_16x16x32_bf16(qh0, kh10, s1, 0, 0, 0);
        s1 = __builtin_amdgcn_mfma_f32_16x16x32_bf16(qh1, kh11, s1, 0, 0, 0);
        s1 = __builtin_amdgcn_mfma_f32_16x16x32_bf16(qh0, kl10, s1, 0, 0, 0);
        s1 = __builtin_amdgcn_mfma_f32_16x16x32_bf16(qh1, kl11, s1, 0, 0, 0);
        s1 = __builtin_amdgcn_mfma_f32_16x16x32_bf16(ql0, kh10, s1, 0, 0, 0);
        s1 = __builtin_amdgcn_mfma_f32_16x16x32_bf16(ql1, kh11, s1, 0, 0, 0);

        float scale[4];
#pragma unroll
        for (int r = 0; r < 4; ++r) {
            float mx = fmaxf(s0[r], s1[r]);
            mx = fmaxf(mx, __shfl_xor(mx, 1));
            mx = fmaxf(mx, __shfl_xor(mx, 2));
            mx = fmaxf(mx, __shfl_xor(mx, 4));
            mx = fmaxf(mx, __shfl_xor(mx, 8));
            float mn = fmaxf(mreg[r], mx);
            float sc = __expf(mreg[r] - mn);
            mreg[r] = mn;
            float p0 = __expf(s0[r] - mn);
            float p1 = __expf(s1[r] - mn);
            lreg[r] = lreg[r] * sc + p0 + p1;     // per-lane partial; reduce at end
            scale[r] = sc;
            pb[g * 4 + r][c]      = f2bf(p0);
            pb[g * 4 + r][16 + c] = f2bf(p1);
        }
#pragma unroll
        for (int r = 0; r < 4; ++r) {
            o0[r] *= scale[r]; o1[r] *= scale[r];
            o2[r] *= scale[r]; o3[r] *= scale[r];
        }
        bf16x8 pa = *(const bf16x8*)&pb[c][g * 8];

        bf16x8 vf0 = *(const bf16x8*)(Vb + ((size_t)(0 * 16 + c)) * SEQ + kb + g * 8);
        bf16x8 vf1 = *(const bf16x8*)(Vb + ((size_t)(1 * 16 + c)) * SEQ + kb + g * 8);
        bf16x8 vf2 = *(const bf16x8*)(Vb + ((size_t)(2 * 16 + c)) * SEQ + kb + g * 8);
        bf16x8 vf3 = *(const bf16x8*)(Vb + ((size_t)(3 * 16 + c)) * SEQ + kb + g * 8);
        o0 = __builtin_amdgcn_mfma_f32_16x16x32_bf16(pa, vf0, o0, 0, 0, 0);
        o1 = __builtin_amdgcn_mfma_f32_16x16x32_bf16(pa, vf1, o1, 0, 0, 0);
        o2 = __builtin_amdgcn_mfma_f32_16x16x32_bf16(pa, vf2, o2, 0, 0, 0);
        o3 = __builtin_amdgcn_mfma_f32_16x16x32_bf16(pa, vf3, o3, 0, 0, 0);
    }

    // deferred cross-lane l reduction
    float ls[4];
#pragma unroll
    for (int r = 0; r < 4; ++r) {
        float t = lreg[r];
        t += __shfl_xor(t, 1);
        t += __shfl_xor(t, 2);
        t += __shfl_xor(t, 4);
        t += __shfl_xor(t, 8);
        ls[r] = t;
    }

    if (normalize) {
        float* Ob = Obuf + ((size_t)b * SEQ + q0) * CH;
#pragma unroll
        for (int r = 0; r < 4; ++r) {
            float inv = 1.f / ls[r];
            Ob[(g * 4 + r) * CH +  0 + c] = o0[r] * inv;
            Ob[(g * 4 + r) * CH + 16 + c] = o1[r] * inv;
            Ob[(g * 4 + r) * CH + 32 + c] = o2[r] * inv;
            Ob[(g * 4 + r) * CH + 48 + c] = o3[r] * inv;
        }
    } else {
        float* Ob = Opart + (size_t)s * (BATCH * SEQ * CH) + ((size_t)b * SEQ + q0) * CH;
#pragma unroll
        for (int r = 0; r < 4; ++r) {
            Ob[(g * 4 + r) * CH +  0 + c] = o0[r];
            Ob[(g * 4 + r) * CH + 16 + c] = o1[r];
            Ob[(g * 4 + r) * CH + 32 + c] = o2[r];
            Ob[(g * 4 + r) * CH + 48 + c] = o3[r];
        }
        if (c == 0) {
#pragma unroll
            for (int r = 0; r < 4; ++r) {
                int row = b * SEQ + q0 + g * 4 + r;
                Mp[s * (BATCH * SEQ) + row] = mreg[r];
                Lp[s * (BATCH * SEQ) + row] = ls[r];
            }
        }
    }
}

// ---------------------------------------------------------------------------
// K2b: combine split partials via log-sum-exp weighting.
// ---------------------------------------------------------------------------
__global__ __launch_bounds__(256) void combine_kernel(
        const float* __restrict__ Opart, const float* __restrict__ Mp,
        const float* __restrict__ Lp, float* __restrict__ Obuf, int nsplit) {
    const int total = BATCH * SEQ * CH;
    for (int idx = blockIdx.x * 256 + threadIdx.x; idx < total; idx += gridDim.x * 256) {
        int row = idx >> 6;
        float M = -1e30f;
        for (int s2 = 0; s2 < nsplit; ++s2) M = fmaxf(M, Mp[s2 * (BATCH * SEQ) + row]);
        float num = 0.f, den = 0.f;
        for (int s2 = 0; s2 < nsplit; ++s2) {
            float w = __expf(Mp[s2 * (BATCH * SEQ) + row] - M);
            den = fmaf(w, Lp[s2 * (BATCH * SEQ) + row], den);
            num = fmaf(w, Opart[(size_t)s2 * total + idx], num);
        }
        Obuf[idx] = num / den;
    }
}

// ---------------------------------------------------------------------------
// K3: final 1x1 conv (fp32 VALU; only 0.5 GFLOP)
// ---------------------------------------------------------------------------
__global__ __launch_bounds__(256) void out_conv_kernel(
        const float* __restrict__ O, const float* __restrict__ wo,
        const float* __restrict__ bo, float* __restrict__ out) {
    int rowblk = blockIdx.x;
    int b  = rowblk / (SEQ / 64);
    int l0 = (rowblk % (SEQ / 64)) * 64;
    __shared__ float Ws[CH][65];
    __shared__ float xs[64][CH];
    int tid = threadIdx.x;
    for (int idx = tid; idx < CH * CH; idx += 256) {
        int i = idx >> 6, cc = idx & 63;
        Ws[cc][i] = wo[idx];
    }
    for (int idx = tid; idx < 64 * CH; idx += 256) {
        int rr = idx >> 6, cc = idx & 63;
        xs[rr][cc] = O[((size_t)b * SEQ + l0 + rr) * CH + cc];
    }
    __syncthreads();
    int wave = tid >> 6, lane = tid & 63;
    int lr0 = wave * 16;
    float acc[16];
    float bias = bo[lane];
#pragma unroll
    for (int r = 0; r < 16; ++r) acc[r] = bias;
    for (int i = 0; i < CH; i += 4) {
        float w0 = Ws[lane][i], w1 = Ws[lane][i + 1], w2 = Ws[lane][i + 2], w3 = Ws[lane][i + 3];
#pragma unroll
        for (int r = 0; r < 16; ++r) {
            const float* xr = &xs[lr0 + r][i];
            acc[r] = fmaf(xr[0], w0, acc[r]);
            acc[r] = fmaf(xr[1], w1, acc[r]);
            acc[r] = fmaf(xr[2], w2, acc[r]);
            acc[r] = fmaf(xr[3], w3, acc[r]);
        }
    }
    float* ob = out + ((size_t)b * SEQ + l0 + lr0) * CH + lane;
#pragma unroll
    for (int r = 0; r < 16; ++r) ob[(size_t)r * CH] = acc[r];
}

// ---------------------------------------------------------------------------
extern "C" void kernel_launch(void* const* d_in, const int* in_sizes, int n_in,
                              void* d_out, int out_size, void* d_ws, size_t ws_size,
                              hipStream_t stream) {
    (void)in_sizes; (void)n_in; (void)out_size;
    const float* Q  = (const float*)d_in[0];
    const float* K  = (const float*)d_in[1];
    const float* V  = (const float*)d_in[2];
    const float* wq = (const float*)d_in[3];
    const float* bq = (const float*)d_in[4];
    const float* wk = (const float*)d_in[5];
    const float* bk = (const float*)d_in[6];
    const float* wv = (const float*)d_in[7];
    const float* bv = (const float*)d_in[8];
    const float* wd = (const float*)d_in[9];
    const float* bd = (const float*)d_in[10];
    const float* wo = (const float*)d_in[11];
    const float* bo = (const float*)d_in[12];
    float* out = (float*)d_out;

    const size_t NEL = (size_t)BATCH * SEQ * CH;   // 2097152
    char* ws = (char*)d_ws;
    unsigned short* Wth = (unsigned short*)(ws);                 // 73728 B
    unsigned short* Wtl = (unsigned short*)(ws + 73728);         // 73728 B
    float* bbp = (float*)(ws + 147456);                          // 2304 B
    unsigned short* Qh = (unsigned short*)(ws + 163840);
    unsigned short* Ql = Qh + NEL;
    unsigned short* Kh = Ql + NEL;
    unsigned short* Kl = Kh + NEL;
    unsigned short* Vt = Kl + NEL;                               // ends at 21135360

    const size_t NEED4 = 64126976, NEED2 = 47349760;
    int NS = (ws_size >= NEED4) ? 4 : (ws_size >= NEED2) ? 2 : 1;

    float *Mp, *Lp, *Opart, *Obuf;
    if (NS > 1) {
        Mp    = (float*)(ws + 21135360);
        Lp    = (float*)(ws + 21659648);
        Opart = (float*)(ws + 22183936);
        Obuf  = (float*)(ws + 22183936 + (size_t)NS * 8388608);
    } else {
        Obuf  = (float*)(ws + 21135360);
        Mp = Lp = Opart = Obuf;   // unused
    }

    combine_w_kernel<<<9, 256, 0, stream>>>(wq, bq, wk, bk, wv, bv, wd, Wth, Wtl, bbp);
    conv_mfma_kernel<<<dim3(512, 3), 256, 0, stream>>>(
        Q, K, V, Wth, Wtl, bbp, bd, Qh, Ql, Kh, Kl, Vt);
    attn_kernel<<<512 * NS, 256, 0, stream>>>(
        Qh, Ql, Kh, Kl, Vt, Opart, Mp, Lp, Obuf, SEQ / NS, (NS == 1) ? 1 : 0);
    if (NS > 1)
        combine_kernel<<<2048, 256, 0, stream>>>(Opart, Mp, Lp, Obuf, NS);
    out_conv_kernel<<<BATCH * SEQ / 64, 256, 0, stream>>>(Obuf, wo, bo, out);
}